// Round 6
// baseline (858.220 us; speedup 1.0000x reference)
//
#include <hip/hip_runtime.h>

#define BATCH 4
#define NN 2048
#define MM 2048
#define DIM 128
#define HID 128

typedef __bf16 bf16x8 __attribute__((ext_vector_type(8)));
typedef float f32x16 __attribute__((ext_vector_type(16)));
typedef float f32x4 __attribute__((ext_vector_type(4)));
typedef float f32x2 __attribute__((ext_vector_type(2)));
typedef unsigned short ushort_t;
typedef ushort_t ushort8 __attribute__((ext_vector_type(8)));
typedef unsigned int uint_t;

#define LOG2E 1.44269504088896340736f
#define LN2   0.69314718055994530942f

__device__ __forceinline__ ushort_t f2bf(float f) {
  uint_t u = __builtin_bit_cast(uint_t, f);
  u += 0x7fffu + ((u >> 16) & 1u);
  return (ushort_t)(u >> 16);
}
__device__ __forceinline__ float bflo(uint_t p) { return __builtin_bit_cast(float, p << 16); }
__device__ __forceinline__ float bfhi(uint_t p) { return __builtin_bit_cast(float, p & 0xffff0000u); }

// ---- pre-kernel: fp32 -> bf16 convert + TILE-MAJOR repack of source_val ----
// Layout (ROUND 6: lane-linear): chunk t = ((b*64 + jt)*8 + ks)*64 + c with
// c == consuming LANE: half = c>>5, l5 = c&31; chunk holds
// S[b][jt*32+l5][ks*16+half*8 .. +8] as 8 bf16.
// Main-kernel ds_read for fixed (jt,ks) is then byte addr = lane*16 (+ks*1KB):
// linear 16B/lane -> 2-way bank aliasing = free (was cc=l5*2+half -> 32B
// stride -> 4-way conflict, SQ_LDS_BANK_CONFLICT 6.7e7). Staging copy and
// global loads stay fully contiguous.
__global__ void cvt_repack(const float* __restrict__ src, ushort_t* __restrict__ dst) {
  int t = blockIdx.x * 256 + threadIdx.x;   // 131072 chunks
  int c    = t & 63;
  int ks   = (t >> 6) & 7;
  int jt   = (t >> 9) & 63;
  int b    = t >> 15;
  int half = c >> 5, l5 = c & 31;           // lane-linear: c == lane
  int j    = jt * 32 + l5;
  int d0   = ks * 16 + half * 8;
  const float* s = src + ((size_t)(b * MM + j)) * DIM + d0;
  float4 v0 = *reinterpret_cast<const float4*>(s);
  float4 v1 = *reinterpret_cast<const float4*>(s + 4);
  ushort8 u;
  u[0] = f2bf(v0.x); u[1] = f2bf(v0.y); u[2] = f2bf(v0.z); u[3] = f2bf(v0.w);
  u[4] = f2bf(v1.x); u[5] = f2bf(v1.y); u[6] = f2bf(v1.z); u[7] = f2bf(v1.w);
  *reinterpret_cast<ushort8*>(dst + (size_t)t * 8) = u;
}

// ---- pre-kernel: pack (b_in*log2e, w_out*ln2) as bf16 pair per h ----
__global__ void pbw_kernel(const float* __restrict__ b_in, const float* __restrict__ w_out,
                           uint_t* __restrict__ pbw) {
  int h = threadIdx.x;
  pbw[h] = (uint_t)f2bf(b_in[h] * LOG2E) | ((uint_t)f2bf(w_out[h] * LN2) << 16);
}

// ---------------- main kernel ----------------
// 8192 blocks = one (b,i); 4 waves; wave wv owns h-quarter [32wv,32wv+32).
// ROUND 6:
//   * launch_bounds BACK to (256,3): (256,4)'s 128-VGPR cap spilled AGAIN
//     (r5: VGPR 64, WRITE_SIZE 65.5->135MB scratch). Twice-confirmed rule:
//     this kernel needs the 3-wave/EU register budget. Occupancy comes from
//     the 24KB LDS footprint instead (6 blocks/CU if VGPR <= ~85).
//   * lane-linear B repack (see cvt_repack) -> conflict-free ds_read_b128.
// Keeps (verified): part1[MM] LDS-atomicAdd reduction (24KB total LDS),
// tile-major B staged in LDS double-buffer (T14 split), cinit bias-fold into
// MFMA C-in, one-time w2 unpack, packed-fp32 epilogue.
__launch_bounds__(256, 3)
__global__ void hmlp_kernel(const float* __restrict__ Tg, const ushort_t* __restrict__ Sb,
                            const float* __restrict__ Wg, const uint_t* __restrict__ pbw,
                            const float* __restrict__ b_out_p, float* __restrict__ Og) {
  __shared__ float part1[MM];          // 8 KB: atomically-accumulated output row
  __shared__ ushort_t Bst[2][4096];    // 16 KB: double-buffered 8KB B tile (one jt)
  const int tid  = threadIdx.x;
  const int lane = tid & 63;
  const int wv   = tid >> 6;
  const int half = lane >> 5;     // lane half (0/1)
  const int l5   = lane & 31;
  const int blk  = blockIdx.x;
  const int b    = blk >> 11;     // 2048 blocks per batch
  const int i    = blk & 2047;
  const int hb   = wv << 5;       // this wave's h-base (0/32/64/96)

  // zero the accumulation row (covered by the prologue barrier below)
  *reinterpret_cast<f32x4*>(&part1[tid * 8])     = (f32x4)(0.f);
  *reinterpret_cast<f32x4*>(&part1[tid * 8 + 4]) = (f32x4)(0.f);

  // one-time unpack: bias' -> MFMA C-in seed, w' -> packed float2 pairs
  // h_r = hb + (r&3) + 8*(r>>2) + 4*half  (C/D row map, verified)
  f32x16 cinit;
  f32x2 w2[8];
#pragma unroll
  for (int r = 0; r < 16; ++r) {
    uint_t pw = pbw[hb + (r & 3) + 8 * (r >> 2) + 4 * half];
    cinit[r] = bflo(pw);
    if (r & 1) w2[r >> 1].y = bfhi(pw); else w2[r >> 1].x = bfhi(pw);
  }

  // ---- A-fragments afr[ks] = bf16(LOG2E * t_i[d] * W[h][d]) ----
  // A row = hb + l5, k(=d) = ks*16 + half*8 + e   (verified)
  bf16x8 afr[8];
  {
    const float* tb = Tg + ((size_t)(b * NN + i)) * DIM;
    const float* wr = Wg + (size_t)(hb + l5) * DIM;
#pragma unroll
    for (int ks = 0; ks < 8; ++ks) {
      const int d0 = ks * 16 + half * 8;
      float4 w0 = *reinterpret_cast<const float4*>(wr + d0);
      float4 w1 = *reinterpret_cast<const float4*>(wr + d0 + 4);
      float4 t0 = *reinterpret_cast<const float4*>(tb + d0);
      float4 t1 = *reinterpret_cast<const float4*>(tb + d0 + 4);
      ushort8 u;
      u[0] = f2bf(w0.x * t0.x * LOG2E); u[1] = f2bf(w0.y * t0.y * LOG2E);
      u[2] = f2bf(w0.z * t0.z * LOG2E); u[3] = f2bf(w0.w * t0.w * LOG2E);
      u[4] = f2bf(w1.x * t1.x * LOG2E); u[5] = f2bf(w1.y * t1.y * LOG2E);
      u[6] = f2bf(w1.z * t1.z * LOG2E); u[7] = f2bf(w1.w * t1.w * LOG2E);
      afr[ks] = __builtin_bit_cast(bf16x8, u);
    }
  }

  // ---- B staging: per jt an 8KB contiguous tile; block copies it to LDS ----
  const ushort_t* stage_base = Sb + (size_t)b * (64 * 4096);

  auto stage_load = [&](int jt, ushort8& s0, ushort8& s1) {
    const ushort_t* p = stage_base + (size_t)jt * 4096 + tid * 8;
    s0 = *reinterpret_cast<const ushort8*>(p);
    s1 = *reinterpret_cast<const ushort8*>(p + 2048);
  };
  auto stage_write = [&](int buf, const ushort8& s0, const ushort8& s1) {
    *reinterpret_cast<ushort8*>(&Bst[buf][tid * 8]) = s0;
    *reinterpret_cast<ushort8*>(&Bst[buf][tid * 8 + 2048]) = s1;
  };

  auto compute = [&](int buf, int jt) {
    // lane's B fragments: 16B at lane*16B + ks*1KB (lane-linear repack)
    const ushort_t* fb = &Bst[buf][lane * 8];
    bf16x8 B0 = *reinterpret_cast<const bf16x8*>(fb);
    bf16x8 B4 = *reinterpret_cast<const bf16x8*>(fb + 4 * 512);
    // two independent 4-deep chains (ILP 2): k 0..63 / k 64..127
    f32x16 c0 = __builtin_amdgcn_mfma_f32_32x32x16_bf16(afr[0], B0, cinit, 0, 0, 0);
    f32x16 c1 = __builtin_amdgcn_mfma_f32_32x32x16_bf16(afr[4], B4, (f32x16)(0.f), 0, 0, 0);
#pragma unroll
    for (int ks = 1; ks < 4; ++ks) {
      bf16x8 Ba = *reinterpret_cast<const bf16x8*>(fb + ks * 512);
      bf16x8 Bb = *reinterpret_cast<const bf16x8*>(fb + (ks + 4) * 512);
      c0 = __builtin_amdgcn_mfma_f32_32x32x16_bf16(afr[ks], Ba, c0, 0, 0, 0);
      c1 = __builtin_amdgcn_mfma_f32_32x32x16_bf16(afr[ks + 4], Bb, c1, 0, 0, 0);
    }

    // epilogue (packed fp32): y log2-domain, p += w'*y*sigmoid; per pair:
    // 1 pk_add + 2 exp2 + 1 pk_add + 2 rcp + 1 pk_mul + 1 pk_fma
    f32x2 pc[4] = {f32x2{0.f, 0.f}, f32x2{0.f, 0.f}, f32x2{0.f, 0.f}, f32x2{0.f, 0.f}};
#define EPI_Q(q)                                                                     \
    {                                                                                \
      f32x2 y = __builtin_shufflevector(c0, c0, 2 * (q), 2 * (q) + 1)                \
              + __builtin_shufflevector(c1, c1, 2 * (q), 2 * (q) + 1);               \
      float e0 = __builtin_amdgcn_exp2f(-y.x);                                       \
      float e1 = __builtin_amdgcn_exp2f(-y.y);                                       \
      f32x2 d = f32x2{e0, e1} + 1.0f;                                                \
      f32x2 s = f32x2{__builtin_amdgcn_rcpf(d.x), __builtin_amdgcn_rcpf(d.y)};       \
      f32x2 ys = y * s;                                                              \
      pc[(q) & 3] = __builtin_elementwise_fma(w2[(q)], ys, pc[(q) & 3]);             \
    }
    EPI_Q(0) EPI_Q(1) EPI_Q(2) EPI_Q(3) EPI_Q(4) EPI_Q(5) EPI_Q(6) EPI_Q(7)
#undef EPI_Q
    f32x2 pv = (pc[0] + pc[1]) + (pc[2] + pc[3]);
    float p = pv.x + pv.y;
    p += __shfl_xor(p, 32, 64);                   // combine lane-halves' h-subsets
    if (lane < 32) atomicAdd(&part1[jt * 32 + l5], p);   // ds_add_f32, no return
  };

  // prologue: stage jt=0 (part1 zeroing above is covered by this barrier)
  ushort8 s0, s1;
  stage_load(0, s0, s1);
  stage_write(0, s0, s1);
  __syncthreads();

#pragma unroll 1
  for (int jt = 0; jt < 64; ++jt) {
    const int buf = jt & 1;
    if (jt + 1 < 64) stage_load(jt + 1, s0, s1);   // issued early, lands under compute
    compute(buf, jt);
    if (jt + 1 < 64) stage_write(buf ^ 1, s0, s1); // write after compute; vmcnt drained here
    __syncthreads();                               // one barrier per jt: buf^1 ready, buf free
  }

  // final: add b_out; contiguous 1KB wave footprints
  {
    const float bo = b_out_p[0];
    const size_t ob = ((size_t)(b * NN + i)) * MM;
#pragma unroll
    for (int k = 0; k < 2; ++k) {
      const int j0 = k * 1024 + tid * 4;
      f32x4 o = *reinterpret_cast<const f32x4*>(&part1[j0]);
      o[0] += bo; o[1] += bo; o[2] += bo; o[3] += bo;
      *reinterpret_cast<f32x4*>(&Og[ob + j0]) = o;
    }
  }
}

// ---------------- launch ----------------
extern "C" void kernel_launch(void* const* d_in, const int* in_sizes, int n_in,
                              void* d_out, int out_size, void* d_ws, size_t ws_size,
                              hipStream_t stream) {
  const float* Tg    = (const float*)d_in[0];
  const float* Sg    = (const float*)d_in[1];
  const float* Wg    = (const float*)d_in[2];
  const float* b_in  = (const float*)d_in[3];
  const float* W_out = (const float*)d_in[4];
  const float* b_out = (const float*)d_in[5];
  float* Og = (float*)d_out;

  ushort_t* Sb = (ushort_t*)d_ws;
  uint_t* pbw  = (uint_t*)((char*)d_ws + (size_t)BATCH * MM * DIM * 2);

  cvt_repack<<<(BATCH * MM * DIM) / (256 * 8), 256, 0, stream>>>(Sg, Sb);
  pbw_kernel<<<1, 128, 0, stream>>>(b_in, W_out, pbw);
  hmlp_kernel<<<BATCH * NN, 256, 0, stream>>>(Tg, Sb, Wg, pbw, b_out, Og);
}

// Round 7
// 793.430 us; speedup vs baseline: 1.0817x; 1.0817x over previous
//
#include <hip/hip_runtime.h>

#define BATCH 4
#define NN 2048
#define MM 2048
#define DIM 128
#define HID 128

typedef __bf16 bf16x8 __attribute__((ext_vector_type(8)));
typedef float f32x16 __attribute__((ext_vector_type(16)));
typedef float f32x4 __attribute__((ext_vector_type(4)));
typedef float f32x2 __attribute__((ext_vector_type(2)));
typedef unsigned short ushort_t;
typedef ushort_t ushort8 __attribute__((ext_vector_type(8)));
typedef unsigned int uint_t;

#define LOG2E 1.44269504088896340736f
#define LN2   0.69314718055994530942f

__device__ __forceinline__ ushort_t f2bf(float f) {
  uint_t u = __builtin_bit_cast(uint_t, f);
  u += 0x7fffu + ((u >> 16) & 1u);
  return (ushort_t)(u >> 16);
}
__device__ __forceinline__ float bflo(uint_t p) { return __builtin_bit_cast(float, p << 16); }
__device__ __forceinline__ float bfhi(uint_t p) { return __builtin_bit_cast(float, p & 0xffff0000u); }

// ---- pre-kernel: fp32 -> bf16 convert + TILE-MAJOR repack of source_val ----
// Lane-linear layout (round-6 verified): chunk t = ((b*64 + jt)*8 + ks)*64 + c
// with c == consuming LANE: half = c>>5, l5 = c&31; chunk holds
// S[b][jt*32+l5][ks*16+half*8 .. +8] as 8 bf16.
// In the main kernel the per-(jt,ks) fragment read is byte addr = lane*16:
// linear 16B/lane -> 2-way bank aliasing = free (conflict counter 6.7e7 -> ~0,
// measured round 6). The same linearity is exactly what global_load_lds needs
// (LDS dest = uniform base + lane*16).
__global__ void cvt_repack(const float* __restrict__ src, ushort_t* __restrict__ dst) {
  int t = blockIdx.x * 256 + threadIdx.x;   // 131072 chunks
  int c    = t & 63;
  int ks   = (t >> 6) & 7;
  int jt   = (t >> 9) & 63;
  int b    = t >> 15;
  int half = c >> 5, l5 = c & 31;           // lane-linear: c == lane
  int j    = jt * 32 + l5;
  int d0   = ks * 16 + half * 8;
  const float* s = src + ((size_t)(b * MM + j)) * DIM + d0;
  float4 v0 = *reinterpret_cast<const float4*>(s);
  float4 v1 = *reinterpret_cast<const float4*>(s + 4);
  ushort8 u;
  u[0] = f2bf(v0.x); u[1] = f2bf(v0.y); u[2] = f2bf(v0.z); u[3] = f2bf(v0.w);
  u[4] = f2bf(v1.x); u[5] = f2bf(v1.y); u[6] = f2bf(v1.z); u[7] = f2bf(v1.w);
  *reinterpret_cast<ushort8*>(dst + (size_t)t * 8) = u;
}

// ---- pre-kernel: pack (b_in*log2e, w_out*ln2) as bf16 pair per h ----
__global__ void pbw_kernel(const float* __restrict__ b_in, const float* __restrict__ w_out,
                           uint_t* __restrict__ pbw) {
  int h = threadIdx.x;
  pbw[h] = (uint_t)f2bf(b_in[h] * LOG2E) | ((uint_t)f2bf(w_out[h] * LN2) << 16);
}

// ---------------- main kernel ----------------
// 8192 blocks = one (b,i); 4 waves; wave wv owns h-quarter [32wv,32wv+32).
// ROUND 7 — recombine verified pieces:
//   * part[4][MM] write-once private rows (round-4 best; round-6's LDS
//     atomicAdd contention was a net loss, occupancy did NOT rise with
//     smaller LDS -> residency is not LDS-gated).
//   * lane-linear repack -> conflict-free ds_read_b128 (round-6 verified).
//   * B staged via __builtin_amdgcn_global_load_lds width=16 (async HBM/L2 ->
//     LDS, no VGPR round-trip, no explicit vmcnt block before barrier; the
//     load has a full compute (~620cy) to cover L2-hit latency (~250cy; Sb is
//     512KB/batch = L2-resident)).
//   * (256,3): thrice-confirmed no-spill register budget.
__launch_bounds__(256, 3)
__global__ void hmlp_kernel(const float* __restrict__ Tg, const ushort_t* __restrict__ Sb,
                            const float* __restrict__ Wg, const uint_t* __restrict__ pbw,
                            const float* __restrict__ b_out_p, float* __restrict__ Og) {
  __shared__ float part[4][MM];        // 32 KB: per-h-quarter output-row partials
  __shared__ ushort_t Bst[2][4096];    // 16 KB: double-buffered 8KB B tile (one jt)
  const int tid  = threadIdx.x;
  const int lane = tid & 63;
  const int wv   = tid >> 6;
  const int half = lane >> 5;     // lane half (0/1)
  const int l5   = lane & 31;
  const int blk  = blockIdx.x;
  const int b    = blk >> 11;     // 2048 blocks per batch
  const int i    = blk & 2047;
  const int hb   = wv << 5;       // this wave's h-base (0/32/64/96)

  // one-time unpack: bias' -> MFMA C-in seed, w' -> packed float2 pairs
  // h_r = hb + (r&3) + 8*(r>>2) + 4*half  (C/D row map, verified)
  f32x16 cinit;
  f32x2 w2[8];
#pragma unroll
  for (int r = 0; r < 16; ++r) {
    uint_t pw = pbw[hb + (r & 3) + 8 * (r >> 2) + 4 * half];
    cinit[r] = bflo(pw);
    if (r & 1) w2[r >> 1].y = bfhi(pw); else w2[r >> 1].x = bfhi(pw);
  }

  // ---- A-fragments afr[ks] = bf16(LOG2E * t_i[d] * W[h][d]) ----
  // A row = hb + l5, k(=d) = ks*16 + half*8 + e   (verified)
  bf16x8 afr[8];
  {
    const float* tb = Tg + ((size_t)(b * NN + i)) * DIM;
    const float* wr = Wg + (size_t)(hb + l5) * DIM;
#pragma unroll
    for (int ks = 0; ks < 8; ++ks) {
      const int d0 = ks * 16 + half * 8;
      float4 w0 = *reinterpret_cast<const float4*>(wr + d0);
      float4 w1 = *reinterpret_cast<const float4*>(wr + d0 + 4);
      float4 t0 = *reinterpret_cast<const float4*>(tb + d0);
      float4 t1 = *reinterpret_cast<const float4*>(tb + d0 + 4);
      ushort8 u;
      u[0] = f2bf(w0.x * t0.x * LOG2E); u[1] = f2bf(w0.y * t0.y * LOG2E);
      u[2] = f2bf(w0.z * t0.z * LOG2E); u[3] = f2bf(w0.w * t0.w * LOG2E);
      u[4] = f2bf(w1.x * t1.x * LOG2E); u[5] = f2bf(w1.y * t1.y * LOG2E);
      u[6] = f2bf(w1.z * t1.z * LOG2E); u[7] = f2bf(w1.w * t1.w * LOG2E);
      afr[ks] = __builtin_bit_cast(bf16x8, u);
    }
  }

  // ---- B staging: async global->LDS, 16B/lane, 2 instrs per wave per jt ----
  // Wave wv covers bytes [wv*2048, wv*2048+2048) of the 8KB tile.
  const ushort_t* stage_base = Sb + (size_t)b * (64 * 4096);

  auto stage_async = [&](int jt, int buf) {
    const ushort_t* g0 = stage_base + (size_t)jt * 4096 + wv * 1024 + lane * 8;
    ushort_t* l0 = &Bst[buf][wv * 1024];
    __builtin_amdgcn_global_load_lds(
        (const __attribute__((address_space(1))) uint_t*)(g0),
        (__attribute__((address_space(3))) uint_t*)(l0), 16, 0, 0);
    __builtin_amdgcn_global_load_lds(
        (const __attribute__((address_space(1))) uint_t*)(g0 + 512),
        (__attribute__((address_space(3))) uint_t*)(l0 + 512), 16, 0, 0);
  };

  auto compute = [&](int buf, int jt) {
    // lane's B fragments: 16B at lane*16 + ks*1KB (lane-linear, conflict-free)
    const ushort_t* fb = &Bst[buf][lane * 8];
    bf16x8 B0 = *reinterpret_cast<const bf16x8*>(fb);
    bf16x8 B4 = *reinterpret_cast<const bf16x8*>(fb + 4 * 512);
    // two independent 4-deep chains (ILP 2): k 0..63 / k 64..127
    f32x16 c0 = __builtin_amdgcn_mfma_f32_32x32x16_bf16(afr[0], B0, cinit, 0, 0, 0);
    f32x16 c1 = __builtin_amdgcn_mfma_f32_32x32x16_bf16(afr[4], B4, (f32x16)(0.f), 0, 0, 0);
#pragma unroll
    for (int ks = 1; ks < 4; ++ks) {
      bf16x8 Ba = *reinterpret_cast<const bf16x8*>(fb + ks * 512);
      bf16x8 Bb = *reinterpret_cast<const bf16x8*>(fb + (ks + 4) * 512);
      c0 = __builtin_amdgcn_mfma_f32_32x32x16_bf16(afr[ks], Ba, c0, 0, 0, 0);
      c1 = __builtin_amdgcn_mfma_f32_32x32x16_bf16(afr[ks + 4], Bb, c1, 0, 0, 0);
    }

    // epilogue (packed fp32): y log2-domain, p += w'*y*sigmoid; per pair:
    // 1 pk_add + 2 exp2 + 1 pk_add + 2 rcp + 1 pk_mul + 1 pk_fma
    f32x2 pc[4] = {f32x2{0.f, 0.f}, f32x2{0.f, 0.f}, f32x2{0.f, 0.f}, f32x2{0.f, 0.f}};
#define EPI_Q(q)                                                                     \
    {                                                                                \
      f32x2 y = __builtin_shufflevector(c0, c0, 2 * (q), 2 * (q) + 1)                \
              + __builtin_shufflevector(c1, c1, 2 * (q), 2 * (q) + 1);               \
      float e0 = __builtin_amdgcn_exp2f(-y.x);                                       \
      float e1 = __builtin_amdgcn_exp2f(-y.y);                                       \
      f32x2 d = f32x2{e0, e1} + 1.0f;                                                \
      f32x2 s = f32x2{__builtin_amdgcn_rcpf(d.x), __builtin_amdgcn_rcpf(d.y)};       \
      f32x2 ys = y * s;                                                              \
      pc[(q) & 3] = __builtin_elementwise_fma(w2[(q)], ys, pc[(q) & 3]);             \
    }
    EPI_Q(0) EPI_Q(1) EPI_Q(2) EPI_Q(3) EPI_Q(4) EPI_Q(5) EPI_Q(6) EPI_Q(7)
#undef EPI_Q
    f32x2 pv = (pc[0] + pc[1]) + (pc[2] + pc[3]);
    float p = pv.x + pv.y;
    p += __shfl_xor(p, 32, 64);                   // combine lane-halves' h-subsets
    if (lane < 32) part[wv][jt * 32 + l5] = p;    // write-once, private row
  };

  // prologue: stage jt=0 into buf 0 (async), barrier drains it
  stage_async(0, 0);
  __syncthreads();

#pragma unroll 1
  for (int jt = 0; jt < 64; ++jt) {
    const int buf = jt & 1;
    if (jt + 1 < 64) stage_async(jt + 1, buf ^ 1);  // async into other buffer
    compute(buf, jt);
    __syncthreads();   // drains vmcnt (gload) + lgkm; buf^1 ready, buf free
  }

  // final: sum 4 h-quarter rows + b_out; contiguous 1KB wave footprints
  {
    const float bo = b_out_p[0];
    const size_t ob = ((size_t)(b * NN + i)) * MM;
#pragma unroll
    for (int k = 0; k < 2; ++k) {
      const int j0 = k * 1024 + tid * 4;
      f32x4 v0 = *reinterpret_cast<const f32x4*>(&part[0][j0]);
      f32x4 v1 = *reinterpret_cast<const f32x4*>(&part[1][j0]);
      f32x4 v2 = *reinterpret_cast<const f32x4*>(&part[2][j0]);
      f32x4 v3 = *reinterpret_cast<const f32x4*>(&part[3][j0]);
      f32x4 o = (v0 + v1) + (v2 + v3);
      o[0] += bo; o[1] += bo; o[2] += bo; o[3] += bo;
      *reinterpret_cast<f32x4*>(&Og[ob + j0]) = o;
    }
  }
}

// ---------------- launch ----------------
extern "C" void kernel_launch(void* const* d_in, const int* in_sizes, int n_in,
                              void* d_out, int out_size, void* d_ws, size_t ws_size,
                              hipStream_t stream) {
  const float* Tg    = (const float*)d_in[0];
  const float* Sg    = (const float*)d_in[1];
  const float* Wg    = (const float*)d_in[2];
  const float* b_in  = (const float*)d_in[3];
  const float* W_out = (const float*)d_in[4];
  const float* b_out = (const float*)d_in[5];
  float* Og = (float*)d_out;

  ushort_t* Sb = (ushort_t*)d_ws;
  uint_t* pbw  = (uint_t*)((char*)d_ws + (size_t)BATCH * MM * DIM * 2);

  cvt_repack<<<(BATCH * MM * DIM) / (256 * 8), 256, 0, stream>>>(Sg, Sb);
  pbw_kernel<<<1, 128, 0, stream>>>(b_in, W_out, pbw);
  hmlp_kernel<<<BATCH * NN, 256, 0, stream>>>(Tg, Sb, Wg, pbw, b_out, Og);
}